// Round 12
// baseline (237.739 us; speedup 1.0000x reference)
//
#include <hip/hip_runtime.h>
#include <stdint.h>

#define LOG2E 1.44269504088896340736f

typedef __attribute__((ext_vector_type(8))) short short8;
typedef __attribute__((ext_vector_type(4))) float float4v;
typedef __attribute__((ext_vector_type(4))) unsigned int uint4v;
typedef __attribute__((ext_vector_type(2))) unsigned int uint2v;

typedef const __attribute__((address_space(1))) unsigned int gu32;
typedef __attribute__((address_space(3))) unsigned int lu32;

__device__ __forceinline__ void async16(const unsigned short* g, unsigned short* l){
  __builtin_amdgcn_global_load_lds((gu32*)g, (lu32*)l, 16, 0, 0);
}

__device__ __forceinline__ unsigned short f2bf(float f){
  union { float f; unsigned int u; } v; v.f = f;
  unsigned int u = v.u;
  return (unsigned short)((u + 0x7FFFu + ((u >> 16) & 1u)) >> 16);
}
// pack two floats to bf16 pair: single HW instruction (RTNE)
__device__ __forceinline__ unsigned int pkbf(float a, float b){
  unsigned int r;
  asm("v_cvt_pk_bf16_f32 %0, %1, %2" : "=v"(r) : "v"(a), "v"(b));
  return r;
}

// permlane swaps (gfx950): exchange 16/32-lane rows between two VGPRs
__device__ __forceinline__ void pl32(unsigned int &a, unsigned int &b){
#if __has_builtin(__builtin_amdgcn_permlane32_swap)
  uint2v r = __builtin_amdgcn_permlane32_swap(a, b, false, false);
  a = r[0]; b = r[1];
#else
  asm("v_permlane32_swap_b32 %0, %1" : "+v"(a), "+v"(b));
#endif
}
__device__ __forceinline__ void pl16(unsigned int &a, unsigned int &b){
#if __has_builtin(__builtin_amdgcn_permlane16_swap)
  uint2v r = __builtin_amdgcn_permlane16_swap(a, b, false, false);
  a = r[0]; b = r[1];
#else
  asm("v_permlane16_swap_b32 %0, %1" : "+v"(a), "+v"(b));
#endif
}

// ---------------- fused prelude: convert x (blocks 0..4095) + transpose W (blocks 4096..5119) ----------------
__global__ void prelude_kernel(const float* __restrict__ x, unsigned short* __restrict__ xb,
                               const float* __restrict__ Wq, const float* __restrict__ Wk,
                               const float* __restrict__ Wv, const float* __restrict__ Wo,
                               unsigned short* __restrict__ wqkvT, unsigned short* __restrict__ woT){
  __shared__ float tileS[64][68];
  const int bid = blockIdx.x;
  if (bid < 4096){
    int t = bid * 256 + threadIdx.x;
    const float4v* xp = (const float4v*)x;
    float4v a = xp[2*t], b = xp[2*t+1];
    short8 o;
    o[0]=(short)f2bf(a[0]); o[1]=(short)f2bf(a[1]); o[2]=(short)f2bf(a[2]); o[3]=(short)f2bf(a[3]);
    o[4]=(short)f2bf(b[0]); o[5]=(short)f2bf(b[1]); o[6]=(short)f2bf(b[2]); o[7]=(short)f2bf(b[3]);
    ((short8*)xb)[t] = o;
    return;
  }
  const int wid = bid - 4096;
  int mat = wid >> 8, tile = wid & 255;
  int tk = tile >> 4, tn = tile & 15;
  const float* W = (mat==0)?Wq:(mat==1)?Wk:(mat==2)?Wv:Wo;
  int k0 = tk*64, n0 = tn*64;
  int tid = threadIdx.x;
  #pragma unroll
  for (int it=0; it<4; ++it){
    int idx = tid + it*256;
    int r = idx >> 4, c4 = idx & 15;
    float4v v = *(const float4v*)&W[(uint64_t)(k0+r)*1024 + n0 + c4*4];
    tileS[r][c4*4+0]=v[0]; tileS[r][c4*4+1]=v[1]; tileS[r][c4*4+2]=v[2]; tileS[r][c4*4+3]=v[3];
  }
  __syncthreads();
  unsigned short* dst; int nbase;
  if (mat<3){ dst = wqkvT; nbase = mat*1024 + n0; } else { dst = woT; nbase = n0; }
  #pragma unroll
  for (int it=0; it<2; ++it){
    int idx = tid + it*256;
    int n = idx >> 3, g = idx & 7;
    short8 o;
    #pragma unroll
    for (int j=0;j<8;++j) o[j] = (short)f2bf(tileS[g*8+j][n]);
    *(short8*)&dst[(uint64_t)(nbase+n)*1024 + k0 + g*8] = o;
  }
}

// ---------------- QKV GEMM, 256x256, TRUE 8-phase counted-vmcnt schedule (r17) ----------------
// m201 port.  C[8192][3072] = A[8192][1024]*BT[3072][1024]^T.  384 blocks x
// 512 thr (8 waves = 2M x 4N), natural mapping by=id&31 (XCD = by%8 owns 4
// M-panels; FETCH 41MB verified in r16).  2 K-tiles/iter: even->buf0,
// odd->buf1.  Phase = { ds_read own frags; stage 1 half-tile; barrier;
// lgkmcnt(0)+sched_barrier; setprio(1); 16 MFMA; setprio(0); [vmcnt(2) at
// P4/P8 only]; barrier }.  Stage rotation P1..P8 = B1(t1),A0(t1),A1(t1),
// B0(t2),B1(t2),A0(t2),A1(t2),B0(t3): each target region's last ds_read
// completed before a strictly earlier closing barrier (checked per-region).
// vmcnt(2) FIFO-waits everything but the newest stage -> all halves a
// phase reads have landed; loads never drain to 0 in-loop (T4).
__global__ __launch_bounds__(512, 2) void gemm_qkv_kernel(
    const unsigned short* __restrict__ A, const unsigned short* __restrict__ BT,
    const float* __restrict__ bias0, const float* __restrict__ bias1, const float* __restrict__ bias2,
    unsigned short* __restrict__ oq, unsigned short* __restrict__ ok,
    unsigned short* __restrict__ ov)
{
  __shared__ __attribute__((aligned(16))) unsigned short lsAll[65536];  // 128 KB
  const int tid = threadIdx.x, lane = tid & 63, wave = tid >> 6;
  const int wr = wave >> 2, wc = wave & 3;          // 2 M-halves x 4 N-quarters
  const int id = blockIdx.x;
  const int by = id & 31, bx = id >> 5;
  const int m0 = by * 256, n0 = bx * 256;
  const int c = lane & 15, quad = lane >> 4;
  const float QSCALE = 0.125f * LOG2E;

  float4v acc[8][4];
  #pragma unroll
  for (int i=0;i<8;++i)
    #pragma unroll
    for (int j=0;j<4;++j) acc[i][j] = (float4v){0.f,0.f,0.f,0.f};

  // stage one half-tile (2 x gload_lds/thread = 16KB): mat 0=A,1=B
  auto STAGEH = [&](int mat, int kt2, int buf, int half){
    const unsigned short* src = mat ? BT : A;
    const int base0 = mat ? 32768 : 0;
    const uint64_t rb = mat ? (uint64_t)n0 : (uint64_t)m0;
    #pragma unroll
    for (int l=0;l<2;++l){
      int fgl = half*1024 + l*512 + tid;
      int row = fgl >> 3, gp = fgl & 7, gs = gp ^ (row & 7);
      async16(&src[(rb+row)*1024 + kt2*64 + gs*8], &lsAll[base0 + buf*16384 + fgl*8]);
    }
  };

  short8 af[4], bf[4];
  auto LOADB = [&](int buf, int kk){
    #pragma unroll
    for (int j=0;j<4;++j){
      int row = wc*64 + j*16 + c;
      int g = (kk*4 + quad) ^ (row & 7);
      bf[j] = *(const short8*)&lsAll[32768 + buf*16384 + row*64 + g*8];
    }
  };
  auto LOADA = [&](int buf, int kk, int mh){
    #pragma unroll
    for (int i4=0;i4<4;++i4){
      int row = wr*128 + mh*64 + i4*16 + c;
      int g = (kk*4 + quad) ^ (row & 7);
      af[i4] = *(const short8*)&lsAll[buf*16384 + row*64 + g*8];
    }
  };
  auto MFMAQ = [&](int mh){
    __builtin_amdgcn_s_setprio(1);
    #pragma unroll
    for (int i4=0;i4<4;++i4)
      #pragma unroll
      for (int j=0;j<4;++j)
        acc[mh*4+i4][j] = __builtin_amdgcn_mfma_f32_16x16x32_bf16(af[i4], bf[j], acc[mh*4+i4][j], 0, 0, 0);
    __builtin_amdgcn_s_setprio(0);
  };

  // prologue: full tile0 (buf0) + B-half0 of tile1 (buf1); wait tile0 only
  #pragma unroll
  for (int h=0;h<2;++h){ STAGEH(0,0,0,h); STAGEH(1,0,0,h); }
  STAGEH(1,1,1,0);
  asm volatile("s_waitcnt vmcnt(2)" ::: "memory");
  __builtin_amdgcn_s_barrier();

  for (int i=0; i<8; ++i){
    const int t1 = 2*i+1, t2 = 2*i+2, t3 = 2*i+3;
    const bool pf = (i < 7);
    // ---- P1: t0 kk0 mh0 | stage B1(t1) ----
    LOADB(0,0); LOADA(0,0,0); STAGEH(1, t1, 1, 1);
    __builtin_amdgcn_s_barrier();
    asm volatile("s_waitcnt lgkmcnt(0)" ::: "memory");
    __builtin_amdgcn_sched_barrier(0);
    MFMAQ(0);
    __builtin_amdgcn_s_barrier();
    // ---- P2: t0 kk0 mh1 | stage A0(t1) ----
    LOADA(0,0,1); STAGEH(0, t1, 1, 0);
    __builtin_amdgcn_s_barrier();
    asm volatile("s_waitcnt lgkmcnt(0)" ::: "memory");
    __builtin_amdgcn_sched_barrier(0);
    MFMAQ(1);
    __builtin_amdgcn_s_barrier();
    // ---- P3: t0 kk1 mh0 | stage A1(t1) ----
    LOADB(0,1); LOADA(0,1,0); STAGEH(0, t1, 1, 1);
    __builtin_amdgcn_s_barrier();
    asm volatile("s_waitcnt lgkmcnt(0)" ::: "memory");
    __builtin_amdgcn_sched_barrier(0);
    MFMAQ(0);
    __builtin_amdgcn_s_barrier();
    // ---- P4: t0 kk1 mh1 | stage B0(t2) | vmcnt ----
    LOADA(0,1,1); if (pf) STAGEH(1, t2, 0, 0);
    __builtin_amdgcn_s_barrier();
    asm volatile("s_waitcnt lgkmcnt(0)" ::: "memory");
    __builtin_amdgcn_sched_barrier(0);
    MFMAQ(1);
    if (pf) asm volatile("s_waitcnt vmcnt(2)" ::: "memory");
    else    asm volatile("s_waitcnt vmcnt(0)" ::: "memory");
    __builtin_amdgcn_s_barrier();
    // ---- P5: t1 kk0 mh0 | stage B1(t2) ----
    LOADB(1,0); LOADA(1,0,0); if (pf) STAGEH(1, t2, 0, 1);
    __builtin_amdgcn_s_barrier();
    asm volatile("s_waitcnt lgkmcnt(0)" ::: "memory");
    __builtin_amdgcn_sched_barrier(0);
    MFMAQ(0);
    __builtin_amdgcn_s_barrier();
    // ---- P6: t1 kk0 mh1 | stage A0(t2) ----
    LOADA(1,0,1); if (pf) STAGEH(0, t2, 0, 0);
    __builtin_amdgcn_s_barrier();
    asm volatile("s_waitcnt lgkmcnt(0)" ::: "memory");
    __builtin_amdgcn_sched_barrier(0);
    MFMAQ(1);
    __builtin_amdgcn_s_barrier();
    // ---- P7: t1 kk1 mh0 | stage A1(t2) ----
    LOADB(1,1); LOADA(1,1,0); if (pf) STAGEH(0, t2, 0, 1);
    __builtin_amdgcn_s_barrier();
    asm volatile("s_waitcnt lgkmcnt(0)" ::: "memory");
    __builtin_amdgcn_sched_barrier(0);
    MFMAQ(0);
    __builtin_amdgcn_s_barrier();
    // ---- P8: t1 kk1 mh1 | stage B0(t3) | vmcnt ----
    LOADA(1,1,1); if (pf) STAGEH(1, t3, 1, 0);
    __builtin_amdgcn_s_barrier();
    asm volatile("s_waitcnt lgkmcnt(0)" ::: "memory");
    __builtin_amdgcn_sched_barrier(0);
    MFMAQ(1);
    if (pf) asm volatile("s_waitcnt vmcnt(2)" ::: "memory");
    __builtin_amdgcn_s_barrier();
  }

  // ---------------- epilogue: bias (+Q scale), repack via 128KB LDS (r16-verified) ----------------
  const int sel = bx >> 2;                       // 0..3 Q, 4..7 K, 8..11 V
  const int n0l = (bx & 3) * 256;
  const int h0 = n0l >> 6;
  const int bb = m0 >> 11, l0 = m0 & 2047;
  const float* bp = (sel==0)?bias0:(sel==1)?bias1:bias2;
  float bj[4];
  #pragma unroll
  for (int j=0;j<4;++j) bj[j] = bp[n0l + wc*64 + j*16 + c];
  __syncthreads();                               // full drain; LDS now free
  unsigned short* lE = lsAll;                    // 256 x 256 bf16
  if (sel < 2){
    unsigned short* dst = (sel==0)?oq:ok;
    #pragma unroll
    for (int i=0;i<8;++i){
      #pragma unroll
      for (int r=0;r<4;++r){
        int row = wr*128 + i*16 + quad*4 + r;
        #pragma unroll
        for (int j=0;j<4;++j){
          float v = acc[i][j][r] + bj[j];
          if (sel == 0) v *= QSCALE;
          int col = wc*64 + j*16 + c;
          int gg = col >> 3;
          int gsw = (gg & 24) | ((gg & 7) ^ (row & 7));
          lE[row*256 + gsw*8 + (col & 7)] = f2bf(v);
        }
      }
    }
    __syncthreads();
    #pragma unroll
    for (int it=0; it<16; ++it){
      int gl = it*512 + tid;
      int row = gl >> 5, gg = gl & 31;
      int gsw = (gg & 24) | ((gg & 7) ^ (row & 7));
      short8 w = *(const short8*)&lE[row*256 + gsw*8];
      int hh = h0 + (gg >> 3);
      *(short8*)&dst[((uint64_t)(bb*16 + hh)*2048 + l0 + row)*64 + (gg & 7)*8] = w;
    }
  } else {
    // V: transposed repack -> store V^T [bh][d][l]
    #pragma unroll
    for (int i=0;i<8;++i){
      #pragma unroll
      for (int r=0;r<4;++r){
        int mloc = wr*128 + i*16 + quad*4 + r;
        int mgg = mloc >> 3;
        #pragma unroll
        for (int j=0;j<4;++j){
          float v = acc[i][j][r] + bj[j];
          int col = wc*64 + j*16 + c;
          int gsT = (mgg & 24) | ((mgg & 7) ^ (col & 7));
          lE[col*256 + gsT*8 + (mloc & 7)] = f2bf(v);
        }
      }
    }
    __syncthreads();
    #pragma unroll
    for (int it=0; it<16; ++it){
      int idx = it*512 + tid;
      int mg = idx & 31, cc = idx >> 5;
      int gsT2 = (mg & 24) | ((mg & 7) ^ (cc & 7));
      short8 w = *(const short8*)&lE[cc*256 + gsT2*8];
      int hh = h0 + (cc >> 6), d = cc & 63;
      *(short8*)&ov[((uint64_t)(bb*16 + hh)*64 + d)*2048 + l0 + mg*8] = w;
    }
  }
}

// ---------------- out-proj GEMM: 128x128 tile, single-buffered (proven 920 TF) ----------------
__global__ __launch_bounds__(256, 3) void gemm_out_kernel(
    const unsigned short* __restrict__ A, const unsigned short* __restrict__ BT,
    const float* __restrict__ bias0, float* __restrict__ of)
{
  __shared__ __attribute__((aligned(16))) unsigned short lS[2*128*64];
  unsigned short* lA = lS;
  unsigned short* lB = lS + 128*64;
  const int tid = threadIdx.x, lane = tid & 63, wave = tid >> 6;
  const int wr = wave >> 1, wc = wave & 1;
  const int by = blockIdx.x & 63, bx = blockIdx.x >> 6;
  const int m0 = by * 128, n0 = bx * 128;
  const int c = lane & 15, quad = lane >> 4;

  float4v acc[4][4];
  #pragma unroll
  for (int i=0;i<4;++i)
    #pragma unroll
    for (int j=0;j<4;++j) acc[i][j] = (float4v){0.f,0.f,0.f,0.f};

  for (int kt = 0; kt < 16; ++kt){
    __syncthreads();
    #pragma unroll
    for (int it=0; it<4; ++it){
      int gl = (wave*4+it)*64 + lane;
      int row = gl >> 3, gp = gl & 7, gs = gp ^ (row & 7);
      async16(&A[(uint64_t)(m0+row)*1024 + kt*64 + gs*8], &lA[gl*8]);
    }
    #pragma unroll
    for (int it=0; it<4; ++it){
      int gl = (wave*4+it)*64 + lane;
      int row = gl >> 3, gp = gl & 7, gs = gp ^ (row & 7);
      async16(&BT[(uint64_t)(n0+row)*1024 + kt*64 + gs*8], &lB[gl*8]);
    }
    __syncthreads();
    #pragma unroll
    for (int kk=0; kk<2; ++kk){
      short8 af[4], bf[4];
      #pragma unroll
      for (int i=0;i<4;++i){
        int row = wr*64 + i*16 + c;
        int g = (quad + kk*4) ^ (row & 7);
        af[i] = *(const short8*)&lA[row*64 + g*8];
      }
      #pragma unroll
      for (int j=0;j<4;++j){
        int row = wc*64 + j*16 + c;
        int g = (quad + kk*4) ^ (row & 7);
        bf[j] = *(const short8*)&lB[row*64 + g*8];
      }
      #pragma unroll
      for (int i=0;i<4;++i)
        #pragma unroll
        for (int j=0;j<4;++j)
          acc[i][j] = __builtin_amdgcn_mfma_f32_16x16x32_bf16(af[i], bf[j], acc[i][j], 0, 0, 0);
    }
  }

  float* lf = (float*)lS;                        // 64 rows x 128 cols fp32 per half
  float bj[4];
  #pragma unroll
  for (int j=0;j<4;++j) bj[j] = bias0[n0 + wc*64 + j*16 + c];
  #pragma unroll
  for (int half=0; half<2; ++half){
    __syncthreads();
    if (wr == half){
      #pragma unroll
      for (int i=0;i<4;++i){
        #pragma unroll
        for (int r=0;r<4;++r){
          int lrow = i*16 + quad*4 + r;
          #pragma unroll
          for (int j=0;j<4;++j){
            int col = wc*64 + j*16 + c;
            int gg = col >> 2;
            int gs2 = (gg & 24) | ((gg & 7) ^ (lrow & 7));
            lf[lrow*128 + gs2*4 + (col & 3)] = acc[i][j][r] + bj[j];
          }
        }
      }
    }
    __syncthreads();
    #pragma unroll
    for (int it=0; it<8; ++it){
      int gl = it*256 + tid;
      int lrow = gl >> 5, gg = gl & 31;
      int gs2 = (gg & 24) | ((gg & 7) ^ (lrow & 7));
      float4v w = *(const float4v*)&lf[lrow*128 + gs2*4];
      *(float4v*)&of[(uint64_t)(m0 + half*64 + lrow)*1024 + n0 + gg*4] = w;
    }
  }
}

// ---------------- flash attention (r9 structure + T5 setprio) ----------------
__global__ __launch_bounds__(256, 3) void attn_kernel(
    const unsigned short* __restrict__ q, const unsigned short* __restrict__ k,
    const unsigned short* __restrict__ vt, unsigned short* __restrict__ o)
{
  __shared__ __attribute__((aligned(16))) unsigned short lK[2][64*64];   // 16 KB
  __shared__ __attribute__((aligned(16))) unsigned short lV[2][64*64];   // 16 KB  V^T [d][key]

  const int idx = blockIdx.x;
  const int bh = idx & 63;          // XCD = bh%8 -> per-XCD K/V working set 4MB
  const int g4 = idx >> 8;          // 0..3
  const int u4 = (idx >> 6) & 3;    // 0..3
  const int qt = (g4==0) ? (15 - u4) : (g4==1) ? (8 + u4) : (g4==2) ? (7 - u4) : u4;
  const int tid = threadIdx.x, lane = tid & 63, wave = tid >> 6;
  const int c = lane & 15, quad = lane >> 4;

  const unsigned short* qh = q  + (uint64_t)bh * (2048*64);
  const unsigned short* kh = k  + (uint64_t)bh * (2048*64);
  const unsigned short* vh = vt + (uint64_t)bh * (64*2048);

  short8 qf[2][2];
  #pragma unroll
  for (int u=0;u<2;++u)
    #pragma unroll
    for (int kk=0;kk<2;++kk){
      int row = qt*128 + u*64 + wave*16 + c;
      qf[u][kk] = *(const short8*)&qh[(uint64_t)row*64 + (kk*4+quad)*8];
    }

  #pragma unroll
  for (int it=0; it<2; ++it){
    int gl = (wave*2+it)*64 + lane;
    int row = gl >> 3, gp = gl & 7, gs = gp ^ (row & 7);
    async16(&kh[(uint64_t)row*64 + gs*8], &lK[0][gl*8]);
    async16(&vh[(uint64_t)row*2048 + gs*8], &lV[0][gl*8]);
  }

  const float4v z4 = {0.f,0.f,0.f,0.f};            // shared C for first-kk QK MFMA
  const uint4v onesu = {0x3F803F80u,0x3F803F80u,0x3F803F80u,0x3F803F80u};
  const short8 ones8 = __builtin_bit_cast(short8, onesu);  // bf16 1.0 x8

  float4v accO[2][4];
  #pragma unroll
  for (int u=0;u<2;++u)
    #pragma unroll
    for (int t=0;t<4;++t) accO[u][t] = z4;
  float4v accL4[2];                                // MFMA row-sum accumulators
  accL4[0] = z4; accL4[1] = z4;

  const int ktEnd = 2*qt + 1;

  for (int kt = 0; kt <= ktEnd; ++kt){
    __syncthreads();
    const int cb = kt & 1;

    if (kt < ktEnd){
      const int nb = 1 - cb;
      #pragma unroll
      for (int it=0; it<2; ++it){
        int gl = (wave*2+it)*64 + lane;
        int row = gl >> 3, gp = gl & 7, gs = gp ^ (row & 7);
        async16(&kh[(uint64_t)((kt+1)*64 + row)*64 + gs*8], &lK[nb][gl*8]);
        async16(&vh[(uint64_t)row*2048 + (kt+1)*64 + gs*8], &lV[nb][gl*8]);
      }
    }

    const bool doU0  = (kt != ktEnd);   // u=0 queries need all but the last key tile
    const bool lastT = (kt == ktEnd);   // u=1 diagonal tile (u=0 inactive)
    const bool diag0 = doU0 && (kt == 2*qt);   // u=0 diagonal tile

    // S^T = K * Q^T : key = kt*64 + j*16 + quad*4 + r, query = qt*128 + u*64 + wave*16 + c
    float4v s[2][4];
    #pragma unroll
    for (int kk=0; kk<2; ++kk){
      short8 kf[4];
      #pragma unroll
      for (int j=0;j<4;++j){
        if (lastT && j > wave) continue;           // fully-masked sub-tile: kf unused
        int row = j*16 + c;
        int g = (kk*4 + quad) ^ (row & 7);
        kf[j] = *(const short8*)&lK[cb][row*64 + g*8];
      }
      __builtin_amdgcn_s_setprio(1);               // T5: favor MFMA-entering wave
      #pragma unroll
      for (int j=0;j<4;++j){
        if (lastT && j > wave) continue;
        s[1][j] = __builtin_amdgcn_mfma_f32_16x16x32_bf16(kf[j], qf[1][kk],
                    (kk==0)? z4 : s[1][j], 0, 0, 0);
      }
      if (doU0){
        #pragma unroll
        for (int j=0;j<4;++j){
          if (diag0 && j > wave) continue;         // fully masked for u0
          s[0][j] = __builtin_amdgcn_mfma_f32_16x16x32_bf16(kf[j], qf[0][kk],
                      (kk==0)? z4 : s[0][j], 0, 0, 0);
        }
      }
      __builtin_amdgcn_s_setprio(0);
    }

    // softmax + in-register repack to PV A-fragments.
    short8 pa[2][2];
    #pragma unroll
    for (int u=1;u>=0;--u){
      if (u==0 && !doU0) continue;
      const bool isDiagU = (u==1) ? lastT : diag0;
      const int qb_u = qt*128 + u*64 + wave*16;
      const bool needMask = (kt*64 + 63 > qb_u);
      const int qg = qb_u + c;
      unsigned int w[4][2];
      #pragma unroll
      for (int j=0;j<4;++j){
        if (isDiagU && j > wave){ w[j][0]=0u; w[j][1]=0u; continue; }
        float p0,p1,p2,p3;
        {
          float4v sv = s[u][j];
          p0 = __builtin_amdgcn_exp2f(sv[0]);
          p1 = __builtin_amdgcn_exp2f(sv[1]);
          p2 = __builtin_amdgcn_exp2f(sv[2]);
          p3 = __builtin_amdgcn_exp2f(sv[3]);
        }
        if (needMask){
          int keyb = kt*64 + j*16 + quad*4;
          if (keyb + 0 > qg) p0 = 0.f;
          if (keyb + 1 > qg) p1 = 0.f;
          if (keyb + 2 > qg) p2 = 0.f;
          if (keyb + 3 > qg) p3 = 0.f;
        }
        w[j][0] = pkbf(p0,p1);
        w[j][1] = pkbf(p2,p3);
      }
      #pragma unroll
      for (int kk=0;kk<2;++kk){
        if (isDiagU && kk==1 && wave < 2) continue;   // pa[u][1] unused downstream
        unsigned int a0 = w[2*kk+0][0], b0 = w[2*kk+1][0];
        unsigned int a1 = w[2*kk+0][1], b1 = w[2*kk+1][1];
        pl32(a0,b0); pl32(a1,b1);
        pl16(a0,b0); pl16(a1,b1);
        uint4v uv; uv[0]=a0; uv[1]=a1; uv[2]=b0; uv[3]=b1;
        pa[u][kk] = __builtin_bit_cast(short8, uv);
      }
    }

    // O += P * V : A = pa (in registers), B = V^T.  lsum by MFMA vs ones.
    #pragma unroll
    for (int kk=0; kk<2; ++kk){
      const bool needU1 = !(lastT && kk==1 && wave < 2);
      const bool needU0 = doU0 && !(diag0 && kk==1 && wave < 2);
      short8 bv[4];
      if (needU1 || needU0){
        #pragma unroll
        for (int t=0;t<4;++t){
          int row = t*16 + c;
          int g = (kk*4 + quad) ^ (row & 7);
          bv[t] = *(const short8*)&lV[cb][row*64 + g*8];
        }
      }
      __builtin_amdgcn_s_setprio(1);               // T5
      if (needU1){
        #pragma unroll
        for (int t=0;t<4;++t)
          accO[1][t] = __builtin_amdgcn_mfma_f32_16x16x32_bf16(pa[1][kk], bv[t], accO[1][t], 0, 0, 0);
        accL4[1] = __builtin_amdgcn_mfma_f32_16x16x32_bf16(pa[1][kk], ones8, accL4[1], 0, 0, 0);
      }
      if (needU0){
        #pragma unroll
        for (int t=0;t<4;++t)
          accO[0][t] = __builtin_amdgcn_mfma_f32_16x16x32_bf16(pa[0][kk], bv[t], accO[0][t], 0, 0, 0);
        accL4[0] = __builtin_amdgcn_mfma_f32_16x16x32_bf16(pa[0][kk], ones8, accL4[0], 0, 0, 0);
      }
      __builtin_amdgcn_s_setprio(0);
    }
  }

  __syncthreads();   // all waves done reading lK/lV; reuse lK as output staging

  const int b = bh >> 4, h = bh & 15;
  unsigned short* lPf = &lK[0][0];
  #pragma unroll
  for (int u=0;u<2;++u){
    #pragma unroll
    for (int r=0;r<4;++r){
      float rinv = 1.0f / accL4[u][r];
      int mloc = u*64 + wave*16 + quad*4 + r;
      #pragma unroll
      for (int t=0;t<4;++t){
        int col = t*16 + c;
        int gg = col >> 3;
        int gs2 = gg ^ (mloc & 7);
        lPf[mloc*64 + gs2*8 + (col & 7)] = f2bf(accO[u][t][r] * rinv);
      }
    }
  }
  __syncthreads();
  #pragma unroll
  for (int it=0; it<4; ++it){
    int gl = it*256 + tid;
    int row = gl >> 3, gg = gl & 7;
    int gs2 = gg ^ (row & 7);
    short8 w = *(const short8*)&lPf[row*64 + gs2*8];
    uint64_t m = (uint64_t)b*2048 + qt*128 + row;
    *(short8*)&o[m*1024 + h*64 + gg*8] = w;
  }
}

extern "C" void kernel_launch(void* const* d_in, const int* in_sizes, int n_in,
                              void* d_out, int out_size, void* d_ws, size_t ws_size,
                              hipStream_t stream)
{
  (void)in_sizes; (void)n_in; (void)out_size; (void)ws_size;
  const float* x  = (const float*)d_in[0];
  const float* Wq = (const float*)d_in[1];
  const float* bq = (const float*)d_in[2];
  const float* Wk = (const float*)d_in[3];
  const float* bk = (const float*)d_in[4];
  const float* Wv = (const float*)d_in[5];
  const float* bv = (const float*)d_in[6];
  const float* Wo = (const float*)d_in[7];
  const float* bo = (const float*)d_in[8];
  float* out = (float*)d_out;

  char* ws = (char*)d_ws;
  unsigned short* xb    = (unsigned short*)(ws);                     // 16 MB (reused as attn out)
  unsigned short* wqkvT = (unsigned short*)(ws + (16ull<<20));       // 6 MB
  unsigned short* woT   = (unsigned short*)(ws + (22ull<<20));       // 2 MB
  unsigned short* qb    = (unsigned short*)(ws + (24ull<<20));       // 16 MB
  unsigned short* kb    = (unsigned short*)(ws + (40ull<<20));       // 16 MB
  unsigned short* vtb   = (unsigned short*)(ws + (56ull<<20));       // 16 MB V^T (written by gemm0)
  unsigned short* ab    = xb;   // x dead after QKV GEMM

  prelude_kernel<<<5120, 256, 0, stream>>>(x, xb, Wq, Wk, Wv, Wo, wqkvT, woT);
  gemm_qkv_kernel<<<384, 512, 0, stream>>>(xb, wqkvT, bq, bk, bv, qb, kb, vtb);
  attn_kernel<<<1024, 256, 0, stream>>>(qb, kb, vtb, ab);
  gemm_out_kernel<<<512, 256, 0, stream>>>(ab, woT, bo, out);
}

// Round 13
// 230.000 us; speedup vs baseline: 1.0336x; 1.0336x over previous
//
#include <hip/hip_runtime.h>
#include <stdint.h>

#define LOG2E 1.44269504088896340736f

typedef __attribute__((ext_vector_type(8))) short short8;
typedef __attribute__((ext_vector_type(4))) float float4v;
typedef __attribute__((ext_vector_type(4))) unsigned int uint4v;
typedef __attribute__((ext_vector_type(2))) unsigned int uint2v;

typedef const __attribute__((address_space(1))) unsigned int gu32;
typedef __attribute__((address_space(3))) unsigned int lu32;

__device__ __forceinline__ void async16(const unsigned short* g, unsigned short* l){
  __builtin_amdgcn_global_load_lds((gu32*)g, (lu32*)l, 16, 0, 0);
}

__device__ __forceinline__ unsigned short f2bf(float f){
  union { float f; unsigned int u; } v; v.f = f;
  unsigned int u = v.u;
  return (unsigned short)((u + 0x7FFFu + ((u >> 16) & 1u)) >> 16);
}
// pack two floats to bf16 pair: single HW instruction (RTNE)
__device__ __forceinline__ unsigned int pkbf(float a, float b){
  unsigned int r;
  asm("v_cvt_pk_bf16_f32 %0, %1, %2" : "=v"(r) : "v"(a), "v"(b));
  return r;
}

// permlane swaps (gfx950): exchange 16/32-lane rows between two VGPRs
__device__ __forceinline__ void pl32(unsigned int &a, unsigned int &b){
#if __has_builtin(__builtin_amdgcn_permlane32_swap)
  uint2v r = __builtin_amdgcn_permlane32_swap(a, b, false, false);
  a = r[0]; b = r[1];
#else
  asm("v_permlane32_swap_b32 %0, %1" : "+v"(a), "+v"(b));
#endif
}
__device__ __forceinline__ void pl16(unsigned int &a, unsigned int &b){
#if __has_builtin(__builtin_amdgcn_permlane16_swap)
  uint2v r = __builtin_amdgcn_permlane16_swap(a, b, false, false);
  a = r[0]; b = r[1];
#else
  asm("v_permlane16_swap_b32 %0, %1" : "+v"(a), "+v"(b));
#endif
}

// ---------------- fused prelude: convert x (blocks 0..4095) + transpose W (blocks 4096..5119) ----------------
__global__ void prelude_kernel(const float* __restrict__ x, unsigned short* __restrict__ xb,
                               const float* __restrict__ Wq, const float* __restrict__ Wk,
                               const float* __restrict__ Wv, const float* __restrict__ Wo,
                               unsigned short* __restrict__ wqkvT, unsigned short* __restrict__ woT){
  __shared__ float tileS[64][68];
  const int bid = blockIdx.x;
  if (bid < 4096){
    int t = bid * 256 + threadIdx.x;
    const float4v* xp = (const float4v*)x;
    float4v a = xp[2*t], b = xp[2*t+1];
    short8 o;
    o[0]=(short)f2bf(a[0]); o[1]=(short)f2bf(a[1]); o[2]=(short)f2bf(a[2]); o[3]=(short)f2bf(a[3]);
    o[4]=(short)f2bf(b[0]); o[5]=(short)f2bf(b[1]); o[6]=(short)f2bf(b[2]); o[7]=(short)f2bf(b[3]);
    ((short8*)xb)[t] = o;
    return;
  }
  const int wid = bid - 4096;
  int mat = wid >> 8, tile = wid & 255;
  int tk = tile >> 4, tn = tile & 15;
  const float* W = (mat==0)?Wq:(mat==1)?Wk:(mat==2)?Wv:Wo;
  int k0 = tk*64, n0 = tn*64;
  int tid = threadIdx.x;
  #pragma unroll
  for (int it=0; it<4; ++it){
    int idx = tid + it*256;
    int r = idx >> 4, c4 = idx & 15;
    float4v v = *(const float4v*)&W[(uint64_t)(k0+r)*1024 + n0 + c4*4];
    tileS[r][c4*4+0]=v[0]; tileS[r][c4*4+1]=v[1]; tileS[r][c4*4+2]=v[2]; tileS[r][c4*4+3]=v[3];
  }
  __syncthreads();
  unsigned short* dst; int nbase;
  if (mat<3){ dst = wqkvT; nbase = mat*1024 + n0; } else { dst = woT; nbase = n0; }
  #pragma unroll
  for (int it=0; it<2; ++it){
    int idx = tid + it*256;
    int n = idx >> 3, g = idx & 7;
    short8 o;
    #pragma unroll
    for (int j=0;j<8;++j) o[j] = (short)f2bf(tileS[g*8+j][n]);
    *(short8*)&dst[(uint64_t)(nbase+n)*1024 + k0 + g*8] = o;
  }
}

// ---------------- GEMM: C[M][N] = A[M][1024] * BT[N][1024]^T, bf16 MFMA ----------------
// 1-D grid, id -> (by = id & 63, bx = id >> 6): XCD = by%8 invariant (8 fixed
// M-rows per XCD -> 2MB A footprint in each private L2; measured FETCH 42MB).
// 128x128 single-buffered m97 structure at its ~920 TF ceiling.  Session
// evidence: explicit dbuf (r10) regressed via occupancy loss; 256^2 coarse
// counted-vmcnt (r16: 70.5us) AND the full m201-style 8-phase schedule
// (r17: 70.0us, correct) both lost to this at K=1024 / 384-block grid
// (1.5 dispatch rounds + short-K prologue share + per-phase barrier
// overhead at 1 block/CU); launch-bounds 2/3/4 all neutral.
template<int EPI>
__global__ __launch_bounds__(256, 3) void gemm_kernel(
    const unsigned short* __restrict__ A, const unsigned short* __restrict__ BT,
    const float* __restrict__ bias0, const float* __restrict__ bias1, const float* __restrict__ bias2,
    unsigned short* __restrict__ oq, unsigned short* __restrict__ ok,
    unsigned short* __restrict__ ov, float* __restrict__ of)
{
  __shared__ __attribute__((aligned(16))) unsigned short lS[2*128*64];
  unsigned short* lA = lS;
  unsigned short* lB = lS + 128*64;
  const int tid = threadIdx.x, lane = tid & 63, wave = tid >> 6;
  const int wr = wave >> 1, wc = wave & 1;
  const int by = blockIdx.x & 63, bx = blockIdx.x >> 6;
  const int m0 = by * 128, n0 = bx * 128;
  const int c = lane & 15, quad = lane >> 4;
  const float QSCALE = 0.125f * LOG2E;

  float4v acc[4][4];
  #pragma unroll
  for (int i=0;i<4;++i)
    #pragma unroll
    for (int j=0;j<4;++j) acc[i][j] = (float4v){0.f,0.f,0.f,0.f};

  for (int kt = 0; kt < 16; ++kt){
    __syncthreads();
    #pragma unroll
    for (int it=0; it<4; ++it){
      int gl = (wave*4+it)*64 + lane;
      int row = gl >> 3, gp = gl & 7, gs = gp ^ (row & 7);
      async16(&A[(uint64_t)(m0+row)*1024 + kt*64 + gs*8], &lA[gl*8]);
    }
    #pragma unroll
    for (int it=0; it<4; ++it){
      int gl = (wave*4+it)*64 + lane;
      int row = gl >> 3, gp = gl & 7, gs = gp ^ (row & 7);
      async16(&BT[(uint64_t)(n0+row)*1024 + kt*64 + gs*8], &lB[gl*8]);
    }
    __syncthreads();
    #pragma unroll
    for (int kk=0; kk<2; ++kk){
      short8 af[4], bf[4];
      #pragma unroll
      for (int i=0;i<4;++i){
        int row = wr*64 + i*16 + c;
        int g = (quad + kk*4) ^ (row & 7);
        af[i] = *(const short8*)&lA[row*64 + g*8];
      }
      #pragma unroll
      for (int j=0;j<4;++j){
        int row = wc*64 + j*16 + c;
        int g = (quad + kk*4) ^ (row & 7);
        bf[j] = *(const short8*)&lB[row*64 + g*8];
      }
      #pragma unroll
      for (int i=0;i<4;++i)
        #pragma unroll
        for (int j=0;j<4;++j)
          acc[i][j] = __builtin_amdgcn_mfma_f32_16x16x32_bf16(af[i], bf[j], acc[i][j], 0, 0, 0);
    }
  }

  if (EPI == 0){
    const int sel = bx >> 3;                       // 0..7 Q, 8..15 K, 16..23 V
    const int n0l = n0 & 1023;
    const int h0 = n0l >> 6;
    const int bb = m0 >> 11, l0 = m0 & 2047;
    const float* bp = (sel==0)?bias0:(sel==1)?bias1:bias2;
    float bj[4];
    #pragma unroll
    for (int j=0;j<4;++j) bj[j] = bp[n0l + wc*64 + j*16 + c];
    __syncthreads();                               // done reading lS for MFMA
    if (sel < 2){
      unsigned short* dst = (sel==0)?oq:ok;
      #pragma unroll
      for (int i=0;i<4;++i){
        #pragma unroll
        for (int r=0;r<4;++r){
          int mloc = wr*64 + i*16 + quad*4 + r;
          #pragma unroll
          for (int j=0;j<4;++j){
            float v = acc[i][j][r] + bj[j];
            if (sel == 0) v *= QSCALE;
            int col = wc*64 + j*16 + c;
            int gg = col >> 3;
            int gs2 = (gg & 8) | ((gg & 7) ^ (mloc & 7));
            lS[mloc*128 + gs2*8 + (col & 7)] = f2bf(v);
          }
        }
      }
      __syncthreads();
      #pragma unroll
      for (int it=0; it<8; ++it){
        int gl = it*256 + tid;
        int row = gl >> 4, gg = gl & 15;
        int gs2 = (gg & 8) | ((gg & 7) ^ (row & 7));
        short8 w = *(const short8*)&lS[row*128 + gs2*8];
        int hh = h0 + (gg >> 3);
        *(short8*)&dst[((uint64_t)(bb*16 + hh)*2048 + l0 + row)*64 + (gg & 7)*8] = w;
      }
    } else {
      // V: transposed repack -> store V^T [bh][d][l]
      #pragma unroll
      for (int i=0;i<4;++i){
        #pragma unroll
        for (int r=0;r<4;++r){
          int mloc = wr*64 + i*16 + quad*4 + r;
          int mgg = mloc >> 3;
          #pragma unroll
          for (int j=0;j<4;++j){
            float v = acc[i][j][r] + bj[j];
            int col = wc*64 + j*16 + c;
            int gsT = (mgg & 8) | ((mgg & 7) ^ (col & 7));
            lS[col*128 + gsT*8 + (mloc & 7)] = f2bf(v);
          }
        }
      }
      __syncthreads();
      #pragma unroll
      for (int it=0; it<8; ++it){
        int idx = it*256 + tid;
        int mg = idx & 15, cc = idx >> 4;
        int gsT2 = (mg & 8) | ((mg & 7) ^ (cc & 7));
        short8 w = *(const short8*)&lS[cc*128 + gsT2*8];
        int hh = h0 + (cc >> 6), d = cc & 63;
        *(short8*)&ov[((uint64_t)(bb*16 + hh)*64 + d)*2048 + l0 + mg*8] = w;
      }
    }
  } else {
    float* lf = (float*)lS;                        // 64 rows x 128 cols fp32 per half
    float bj[4];
    #pragma unroll
    for (int j=0;j<4;++j) bj[j] = bias0[n0 + wc*64 + j*16 + c];
    #pragma unroll
    for (int half=0; half<2; ++half){
      __syncthreads();
      if (wr == half){
        #pragma unroll
        for (int i=0;i<4;++i){
          #pragma unroll
          for (int r=0;r<4;++r){
            int lrow = i*16 + quad*4 + r;
            #pragma unroll
            for (int j=0;j<4;++j){
              int col = wc*64 + j*16 + c;
              int gg = col >> 2;
              int gs2 = (gg & 24) | ((gg & 7) ^ (lrow & 7));
              lf[lrow*128 + gs2*4 + (col & 3)] = acc[i][j][r] + bj[j];
            }
          }
        }
      }
      __syncthreads();
      #pragma unroll
      for (int it=0; it<8; ++it){
        int gl = it*256 + tid;
        int lrow = gl >> 5, gg = gl & 31;
        int gs2 = (gg & 24) | ((gg & 7) ^ (lrow & 7));
        float4v w = *(const float4v*)&lf[lrow*128 + gs2*4];
        *(float4v*)&of[(uint64_t)(m0 + half*64 + lrow)*1024 + n0 + gg*4] = w;
      }
    }
  }
}

// ---------------- flash attention (r9 structure + T5 setprio) ----------------
// Structure summary (session-verified): swapped QK^T -> P query-column-local;
// in-register P repack via permlane32/16_swap (zero LDS for P, bank
// conflicts 0); Q direct from global; lsum via MFMA against ones-fragment;
// diagonal-tile skips; (256,3) -- 4 waves/EU spills (unified reg demand
// 84 arch + 40 acc = 124 > granularity headroom at 128 budget).
__global__ __launch_bounds__(256, 3) void attn_kernel(
    const unsigned short* __restrict__ q, const unsigned short* __restrict__ k,
    const unsigned short* __restrict__ vt, unsigned short* __restrict__ o)
{
  __shared__ __attribute__((aligned(16))) unsigned short lK[2][64*64];   // 16 KB
  __shared__ __attribute__((aligned(16))) unsigned short lV[2][64*64];   // 16 KB  V^T [d][key]

  const int idx = blockIdx.x;
  const int bh = idx & 63;          // XCD = bh%8 -> per-XCD K/V working set 4MB
  const int g4 = idx >> 8;          // 0..3
  const int u4 = (idx >> 6) & 3;    // 0..3
  const int qt = (g4==0) ? (15 - u4) : (g4==1) ? (8 + u4) : (g4==2) ? (7 - u4) : u4;
  const int tid = threadIdx.x, lane = tid & 63, wave = tid >> 6;
  const int c = lane & 15, quad = lane >> 4;

  const unsigned short* qh = q  + (uint64_t)bh * (2048*64);
  const unsigned short* kh = k  + (uint64_t)bh * (2048*64);
  const unsigned short* vh = vt + (uint64_t)bh * (64*2048);

  short8 qf[2][2];
  #pragma unroll
  for (int u=0;u<2;++u)
    #pragma unroll
    for (int kk=0;kk<2;++kk){
      int row = qt*128 + u*64 + wave*16 + c;
      qf[u][kk] = *(const short8*)&qh[(uint64_t)row*64 + (kk*4+quad)*8];
    }

  #pragma unroll
  for (int it=0; it<2; ++it){
    int gl = (wave*2+it)*64 + lane;
    int row = gl >> 3, gp = gl & 7, gs = gp ^ (row & 7);
    async16(&kh[(uint64_t)row*64 + gs*8], &lK[0][gl*8]);
    async16(&vh[(uint64_t)row*2048 + gs*8], &lV[0][gl*8]);
  }

  const float4v z4 = {0.f,0.f,0.f,0.f};            // shared C for first-kk QK MFMA
  const uint4v onesu = {0x3F803F80u,0x3F803F80u,0x3F803F80u,0x3F803F80u};
  const short8 ones8 = __builtin_bit_cast(short8, onesu);  // bf16 1.0 x8

  float4v accO[2][4];
  #pragma unroll
  for (int u=0;u<2;++u)
    #pragma unroll
    for (int t=0;t<4;++t) accO[u][t] = z4;
  float4v accL4[2];                                // MFMA row-sum accumulators
  accL4[0] = z4; accL4[1] = z4;

  const int ktEnd = 2*qt + 1;

  for (int kt = 0; kt <= ktEnd; ++kt){
    __syncthreads();
    const int cb = kt & 1;

    if (kt < ktEnd){
      const int nb = 1 - cb;
      #pragma unroll
      for (int it=0; it<2; ++it){
        int gl = (wave*2+it)*64 + lane;
        int row = gl >> 3, gp = gl & 7, gs = gp ^ (row & 7);
        async16(&kh[(uint64_t)((kt+1)*64 + row)*64 + gs*8], &lK[nb][gl*8]);
        async16(&vh[(uint64_t)row*2048 + (kt+1)*64 + gs*8], &lV[nb][gl*8]);
      }
    }

    const bool doU0  = (kt != ktEnd);   // u=0 queries need all but the last key tile
    const bool lastT = (kt == ktEnd);   // u=1 diagonal tile (u=0 inactive)
    const bool diag0 = doU0 && (kt == 2*qt);   // u=0 diagonal tile

    // S^T = K * Q^T : key = kt*64 + j*16 + quad*4 + r, query = qt*128 + u*64 + wave*16 + c
    float4v s[2][4];
    #pragma unroll
    for (int kk=0; kk<2; ++kk){
      short8 kf[4];
      #pragma unroll
      for (int j=0;j<4;++j){
        if (lastT && j > wave) continue;           // fully-masked sub-tile: kf unused
        int row = j*16 + c;
        int g = (kk*4 + quad) ^ (row & 7);
        kf[j] = *(const short8*)&lK[cb][row*64 + g*8];
      }
      __builtin_amdgcn_s_setprio(1);               // T5: favor MFMA-entering wave
      #pragma unroll
      for (int j=0;j<4;++j){
        if (lastT && j > wave) continue;
        s[1][j] = __builtin_amdgcn_mfma_f32_16x16x32_bf16(kf[j], qf[1][kk],
                    (kk==0)? z4 : s[1][j], 0, 0, 0);
      }
      if (doU0){
        #pragma unroll
        for (int j=0;j<4;++j){
          if (diag0 && j > wave) continue;         // fully masked for u0
          s[0][j] = __builtin_amdgcn_mfma_f32_16x16x32_bf16(kf[j], qf[0][kk],
                      (kk==0)? z4 : s[0][j], 0, 0, 0);
        }
      }
      __builtin_amdgcn_s_setprio(0);
    }

    // softmax + in-register repack to PV A-fragments.
    short8 pa[2][2];
    #pragma unroll
    for (int u=1;u>=0;--u){
      if (u==0 && !doU0) continue;
      const bool isDiagU = (u==1) ? lastT : diag0;
      const int qb_u = qt*128 + u*64 + wave*16;
      const bool needMask = (kt*64 + 63 > qb_u);
      const int qg = qb_u + c;
      unsigned int w[4][2];
      #pragma unroll
      for (int j=0;j<4;++j){
        if (isDiagU && j > wave){ w[j][0]=0u; w[j][1]=0u; continue; }
        float p0,p1,p2,p3;
        {
          float4v sv = s[u][j];
          p0 = __builtin_amdgcn_exp2f(sv[0]);
          p1 = __builtin_amdgcn_exp2f(sv[1]);
          p2 = __builtin_amdgcn_exp2f(sv[2]);
          p3 = __builtin_amdgcn_exp2f(sv[3]);
        }
        if (needMask){
          int keyb = kt*64 + j*16 + quad*4;
          if (keyb + 0 > qg) p0 = 0.f;
          if (keyb + 1 > qg) p1 = 0.f;
          if (keyb + 2 > qg) p2 = 0.f;
          if (keyb + 3 > qg) p3 = 0.f;
        }
        w[j][0] = pkbf(p0,p1);
        w[j][1] = pkbf(p2,p3);
      }
      #pragma unroll
      for (int kk=0;kk<2;++kk){
        if (isDiagU && kk==1 && wave < 2) continue;   // pa[u][1] unused downstream
        unsigned int a0 = w[2*kk+0][0], b0 = w[2*kk+1][0];
        unsigned int a1 = w[2*kk+0][1], b1 = w[2*kk+1][1];
        pl32(a0,b0); pl32(a1,b1);
        pl16(a0,b0); pl16(a1,b1);
        uint4v uv; uv[0]=a0; uv[1]=a1; uv[2]=b0; uv[3]=b1;
        pa[u][kk] = __builtin_bit_cast(short8, uv);
      }
    }

    // O += P * V : A = pa (in registers), B = V^T.  lsum by MFMA vs ones.
    #pragma unroll
    for (int kk=0; kk<2; ++kk){
      const bool needU1 = !(lastT && kk==1 && wave < 2);
      const bool needU0 = doU0 && !(diag0 && kk==1 && wave < 2);
      short8 bv[4];
      if (needU1 || needU0){
        #pragma unroll
        for (int t=0;t<4;++t){
          int row = t*16 + c;
          int g = (kk*4 + quad) ^ (row & 7);
          bv[t] = *(const short8*)&lV[cb][row*64 + g*8];
        }
      }
      __builtin_amdgcn_s_setprio(1);               // T5
      if (needU1){
        #pragma unroll
        for (int t=0;t<4;++t)
          accO[1][t] = __builtin_amdgcn_mfma_f32_16x16x32_bf16(pa[1][kk], bv[t], accO[1][t], 0, 0, 0);
        accL4[1] = __builtin_amdgcn_mfma_f32_16x16x32_bf16(pa[1][kk], ones8, accL4[1], 0, 0, 0);
      }
      if (needU0){
        #pragma unroll
        for (int t=0;t<4;++t)
          accO[0][t] = __builtin_amdgcn_mfma_f32_16x16x32_bf16(pa[0][kk], bv[t], accO[0][t], 0, 0, 0);
        accL4[0] = __builtin_amdgcn_mfma_f32_16x16x32_bf16(pa[0][kk], ones8, accL4[0], 0, 0, 0);
      }
      __builtin_amdgcn_s_setprio(0);
    }
  }

  __syncthreads();   // all waves done reading lK/lV; reuse lK as output staging

  const int b = bh >> 4, h = bh & 15;
  unsigned short* lPf = &lK[0][0];
  #pragma unroll
  for (int u=0;u<2;++u){
    #pragma unroll
    for (int r=0;r<4;++r){
      float rinv = 1.0f / accL4[u][r];
      int mloc = u*64 + wave*16 + quad*4 + r;
      #pragma unroll
      for (int t=0;t<4;++t){
        int col = t*16 + c;
        int gg = col >> 3;
        int gs2 = gg ^ (mloc & 7);
        lPf[mloc*64 + gs2*8 + (col & 7)] = f2bf(accO[u][t][r] * rinv);
      }
    }
  }
  __syncthreads();
  #pragma unroll
  for (int it=0; it<4; ++it){
    int gl = it*256 + tid;
    int row = gl >> 3, gg = gl & 7;
    int gs2 = gg ^ (row & 7);
    short8 w = *(const short8*)&lPf[row*64 + gs2*8];
    uint64_t m = (uint64_t)b*2048 + qt*128 + row;
    *(short8*)&o[m*1024 + h*64 + gg*8] = w;
  }
}

extern "C" void kernel_launch(void* const* d_in, const int* in_sizes, int n_in,
                              void* d_out, int out_size, void* d_ws, size_t ws_size,
                              hipStream_t stream)
{
  (void)in_sizes; (void)n_in; (void)out_size; (void)ws_size;
  const float* x  = (const float*)d_in[0];
  const float* Wq = (const float*)d_in[1];
  const float* bq = (const float*)d_in[2];
  const float* Wk = (const float*)d_in[3];
  const float* bk = (const float*)d_in[4];
  const float* Wv = (const float*)d_in[5];
  const float* bv = (const float*)d_in[6];
  const float* Wo = (const float*)d_in[7];
  const float* bo = (const float*)d_in[8];
  float* out = (float*)d_out;

  char* ws = (char*)d_ws;
  unsigned short* xb    = (unsigned short*)(ws);                     // 16 MB (reused as attn out)
  unsigned short* wqkvT = (unsigned short*)(ws + (16ull<<20));       // 6 MB
  unsigned short* woT   = (unsigned short*)(ws + (22ull<<20));       // 2 MB
  unsigned short* qb    = (unsigned short*)(ws + (24ull<<20));       // 16 MB
  unsigned short* kb    = (unsigned short*)(ws + (40ull<<20));       // 16 MB
  unsigned short* vtb   = (unsigned short*)(ws + (56ull<<20));       // 16 MB V^T (written by gemm0)
  unsigned short* ab    = xb;   // x dead after QKV GEMM

  prelude_kernel<<<5120, 256, 0, stream>>>(x, xb, Wq, Wk, Wv, Wo, wqkvT, woT);
  gemm_kernel<0><<<1536, 256, 0, stream>>>(xb, wqkvT, bq, bk, bv, qb, kb, vtb, nullptr);
  attn_kernel<<<1024, 256, 0, stream>>>(qb, kb, vtb, ab);
  gemm_kernel<1><<<512, 256, 0, stream>>>(ab, woT, bo, nullptr, nullptr, nullptr, nullptr, nullptr, out);
}